// Round 2
// baseline (1199.729 us; speedup 1.0000x reference)
//
#include <hip/hip_runtime.h>
#include <hip/hip_bf16.h>
#include <math.h>

#define DEV __device__ __forceinline__

DEV float bf2f(unsigned short u) {
    union { unsigned int i; float f; } c; c.i = ((unsigned int)u) << 16; return c.f;
}
DEV unsigned short f2bf(float f) {
    union { float f; unsigned int u; } c; c.f = f;
    unsigned int u = c.u;
    unsigned int r = u + 0x7fffu + ((u >> 16) & 1u);
    return (unsigned short)(r >> 16);
}

// ---------------- input-dtype detector ----------------
// If inputs are bf16, even-index ushorts of W0 are genuine bf16 values of
// 0.1*N(0,1) -> exponent field in [110,132] ~always. If inputs are fp32,
// even-index ushorts are low mantissa bits (~uniform) -> ~9% in range.
__global__ void detect_kernel(const unsigned short* __restrict__ w, int* __restrict__ flag) {
    __shared__ int cnt;
    if (threadIdx.x == 0) cnt = 0;
    __syncthreads();
    int c = 0;
    for (int i = threadIdx.x; i < 2048; i += 256) {
        unsigned short u = w[i * 2];
        int e = (u >> 7) & 0xff;
        if (e >= 110 && e <= 132) c++;
    }
    atomicAdd(&cnt, c);
    __syncthreads();
    if (threadIdx.x == 0) *flag = (cnt > 1024) ? 1 : 0;
}

// ---------------- CSR build ----------------

__global__ void zero_kernel(int* __restrict__ p, int n) {
    int i = blockIdx.x * 256 + threadIdx.x;
    if (i < n) p[i] = 0;
}

__global__ void degree_kernel(const int* __restrict__ dst, int* __restrict__ deg, int E) {
    int i = blockIdx.x * 256 + threadIdx.x;
    if (i < E) atomicAdd(&deg[dst[i]], 1);
}

__global__ __launch_bounds__(1024)
void scan_kernel(const int* __restrict__ deg, int* __restrict__ rowptr, int n) {
    __shared__ int wtot[16];
    const int tid  = threadIdx.x;
    const int lane = tid & 63;
    const int wid  = tid >> 6;
    int carry = 0;
    for (int base = 0; base < n; base += 4096) {
        int i0 = base + tid * 4;
        int v0 = (i0     < n) ? deg[i0]     : 0;
        int v1 = (i0 + 1 < n) ? deg[i0 + 1] : 0;
        int v2 = (i0 + 2 < n) ? deg[i0 + 2] : 0;
        int v3 = (i0 + 3 < n) ? deg[i0 + 3] : 0;
        int s = v0 + v1 + v2 + v3;
        int sc = s;
        #pragma unroll
        for (int d = 1; d < 64; d <<= 1) {
            int t = __shfl_up(sc, d);
            if (lane >= d) sc += t;
        }
        if (lane == 63) wtot[wid] = sc;
        __syncthreads();
        int woff = 0, tot = 0;
        #pragma unroll
        for (int w = 0; w < 16; ++w) {
            int t = wtot[w];
            if (w < wid) woff += t;
            tot += t;
        }
        int p = carry + woff + (sc - s);   // exclusive prefix at i0
        if (i0     < n) rowptr[i0]     = p; p += v0;
        if (i0 + 1 < n) rowptr[i0 + 1] = p; p += v1;
        if (i0 + 2 < n) rowptr[i0 + 2] = p; p += v2;
        if (i0 + 3 < n) rowptr[i0 + 3] = p;
        carry += tot;
        __syncthreads();
    }
    if (tid == 0) rowptr[n] = carry;
}

__global__ void scatter_kernel(const int* __restrict__ src, const int* __restrict__ dst,
                               const void* __restrict__ ew, const int* __restrict__ flagp,
                               const int* __restrict__ rowptr, int* __restrict__ cur,
                               int* __restrict__ csr_src, float* __restrict__ csr_w, int E) {
    int i = blockIdx.x * 256 + threadIdx.x;
    if (i < E) {
        int isbf = *flagp;
        int d = dst[i];
        int pos = atomicAdd(&cur[d], 1);
        int slot = rowptr[d] + pos;
        csr_src[slot] = src[i];
        csr_w[slot] = isbf ? bf2f(((const unsigned short*)ew)[i]) : ((const float*)ew)[i];
    }
}

// ---------------- GEMM: C[M,128] = A[M,K] @ B[K,128], fp32 accumulate ----------------
// AEXT: A is an external input (dtype per flag). Otherwise A = internal fp32.
// B is always an external weight (dtype per flag).
// write_bf16: C stored as bf16 (feat) or fp32 (res0).

template <int AEXT>
__global__ __launch_bounds__(256)
void gemm_kernel(const void* __restrict__ Aext, const float* __restrict__ Aint,
                 const void* __restrict__ Bv, void* __restrict__ Cout,
                 const int* __restrict__ flagp, int write_bf16, int M, int K) {
    __shared__ __align__(16) float As[64][20];   // [row][k], row stride 80 B
    __shared__ __align__(16) float Bs[16][128];  // [k][col]
    const int isbf = *flagp;
    const int tid  = threadIdx.x;
    const long brow = (long)blockIdx.x * 64;
    const int rb   = (tid >> 5) * 8;     // 8-row group
    const int colq = tid & 31;           // 4-col group
    float acc[8][4];
    #pragma unroll
    for (int r = 0; r < 8; ++r) { acc[r][0]=0.f; acc[r][1]=0.f; acc[r][2]=0.f; acc[r][3]=0.f; }

    const int lr = tid >> 2;            // A tile: row 0..63
    const int lk = (tid & 3) * 4;       // A tile: k 0,4,8,12
    const int bk = tid >> 4;            // B tile: k 0..15
    const int bc = (tid & 15) * 8;      // B tile: col 0..120

    for (int k0 = 0; k0 < K; k0 += 16) {
        long ga = brow + lr;
        float4 av = make_float4(0.f, 0.f, 0.f, 0.f);
        if (ga < M) {
            if (AEXT) {
                if (isbf) {
                    const unsigned short* ap = (const unsigned short*)Aext + ga * K + k0 + lk;
                    ushort4 u = *(const ushort4*)ap;
                    av.x = bf2f(u.x); av.y = bf2f(u.y); av.z = bf2f(u.z); av.w = bf2f(u.w);
                } else {
                    av = *(const float4*)((const float*)Aext + ga * K + k0 + lk);
                }
            } else {
                av = *(const float4*)(Aint + ga * K + k0 + lk);
            }
        }
        *(float4*)&As[lr][lk] = av;
        if (isbf) {
            const unsigned short* bp = (const unsigned short*)Bv + (long)(k0 + bk) * 128 + bc;
            uint4 u = *(const uint4*)bp;
            float4 lo, hi;
            lo.x = bf2f((unsigned short)(u.x & 0xffffu)); lo.y = bf2f((unsigned short)(u.x >> 16));
            lo.z = bf2f((unsigned short)(u.y & 0xffffu)); lo.w = bf2f((unsigned short)(u.y >> 16));
            hi.x = bf2f((unsigned short)(u.z & 0xffffu)); hi.y = bf2f((unsigned short)(u.z >> 16));
            hi.z = bf2f((unsigned short)(u.w & 0xffffu)); hi.w = bf2f((unsigned short)(u.w >> 16));
            *(float4*)&Bs[bk][bc]     = lo;
            *(float4*)&Bs[bk][bc + 4] = hi;
        } else {
            const float* bp = (const float*)Bv + (long)(k0 + bk) * 128 + bc;
            *(float4*)&Bs[bk][bc]     = *(const float4*)bp;
            *(float4*)&Bs[bk][bc + 4] = *(const float4*)(bp + 4);
        }
        __syncthreads();
        #pragma unroll
        for (int kq = 0; kq < 4; ++kq) {
            float4 b0 = *(float4*)&Bs[kq*4+0][colq*4];
            float4 b1 = *(float4*)&Bs[kq*4+1][colq*4];
            float4 b2 = *(float4*)&Bs[kq*4+2][colq*4];
            float4 b3 = *(float4*)&Bs[kq*4+3][colq*4];
            #pragma unroll
            for (int r = 0; r < 8; ++r) {
                float4 a4 = *(float4*)&As[rb + r][kq*4];
                acc[r][0] = fmaf(a4.x,b0.x, fmaf(a4.y,b1.x, fmaf(a4.z,b2.x, fmaf(a4.w,b3.x, acc[r][0]))));
                acc[r][1] = fmaf(a4.x,b0.y, fmaf(a4.y,b1.y, fmaf(a4.z,b2.y, fmaf(a4.w,b3.y, acc[r][1]))));
                acc[r][2] = fmaf(a4.x,b0.z, fmaf(a4.y,b1.z, fmaf(a4.z,b2.z, fmaf(a4.w,b3.z, acc[r][2]))));
                acc[r][3] = fmaf(a4.x,b0.w, fmaf(a4.y,b1.w, fmaf(a4.z,b2.w, fmaf(a4.w,b3.w, acc[r][3]))));
            }
        }
        __syncthreads();
    }
    const int col = colq * 4;
    #pragma unroll
    for (int r = 0; r < 8; ++r) {
        long grow = brow + rb + r;
        if (grow < M) {
            if (write_bf16) {
                ushort4 o;
                o.x = f2bf(acc[r][0]); o.y = f2bf(acc[r][1]);
                o.z = f2bf(acc[r][2]); o.w = f2bf(acc[r][3]);
                *(ushort4*)((unsigned short*)Cout + grow * 128 + col) = o;
            } else {
                *(float4*)((float*)Cout + grow * 128 + col) =
                    make_float4(acc[r][0], acc[r][1], acc[r][2], acc[r][3]);
            }
        }
    }
}

// ---------------- el/er: per (node, head) dot of bf16 feat with al/ar ----------------

__global__ __launch_bounds__(256)
void elr_kernel(const unsigned short* __restrict__ featu,
                const void* __restrict__ al, const void* __restrict__ ar,
                const int* __restrict__ flagp,
                float* __restrict__ el, float* __restrict__ er, int N) {
    int idx = blockIdx.x * 256 + threadIdx.x;
    if (idx >= N * 4) return;
    const int isbf = *flagp;
    int n = idx >> 2, h = idx & 3;
    const unsigned short* fr = featu + (long)n * 128 + h * 32;
    float av[32], bv[32];
    if (isbf) {
        const unsigned short* alp = (const unsigned short*)al + h * 32;
        const unsigned short* arp = (const unsigned short*)ar + h * 32;
        #pragma unroll
        for (int i = 0; i < 32; ++i) { av[i] = bf2f(alp[i]); bv[i] = bf2f(arp[i]); }
    } else {
        const float* alp = (const float*)al + h * 32;
        const float* arp = (const float*)ar + h * 32;
        #pragma unroll
        for (int i = 0; i < 32; ++i) { av[i] = alp[i]; bv[i] = arp[i]; }
    }
    float sl = 0.f, sr = 0.f;
    #pragma unroll
    for (int i = 0; i < 32; i += 8) {
        uint4 u = *(const uint4*)&fr[i];
        float f[8];
        f[0] = bf2f((unsigned short)(u.x & 0xffffu)); f[1] = bf2f((unsigned short)(u.x >> 16));
        f[2] = bf2f((unsigned short)(u.y & 0xffffu)); f[3] = bf2f((unsigned short)(u.y >> 16));
        f[4] = bf2f((unsigned short)(u.z & 0xffffu)); f[5] = bf2f((unsigned short)(u.z >> 16));
        f[6] = bf2f((unsigned short)(u.w & 0xffffu)); f[7] = bf2f((unsigned short)(u.w >> 16));
        #pragma unroll
        for (int j = 0; j < 8; ++j) { sl += f[j] * av[i + j]; sr += f[j] * bv[i + j]; }
    }
    el[idx] = sl; er[idx] = sr;
}

// ---------------- fused: edge softmax + aggregate + residual + bias + ELU + LayerNorm ----------------
// one wave per node; lane = 2 output features; online softmax over in-edge chunks of 64

__global__ __launch_bounds__(256)
void aggregate_kernel(const unsigned short* __restrict__ featu,
                      const float4* __restrict__ el4,
                      const float4* __restrict__ er4,
                      const float* __restrict__ res,
                      const void* __restrict__ bias,
                      const void* __restrict__ lng,
                      const void* __restrict__ lnb,
                      const int* __restrict__ flagp,
                      const int* __restrict__ rowptr,
                      const int* __restrict__ csr_src,
                      const float* __restrict__ csr_w,
                      float* __restrict__ out_f32,
                      unsigned short* __restrict__ out_u16,
                      int N, int apply_elu, int final_mode) {
    const int lane = threadIdx.x & 63;
    const int wid  = threadIdx.x >> 6;
    const int v = blockIdx.x * 4 + wid;
    if (v >= N) return;
    const int isbf = *flagp;
    const int hd = lane >> 4;        // head of this lane's features
    const int f0 = lane * 2;         // features f0, f0+1
    const int p0 = rowptr[v], p1 = rowptr[v + 1];
    const float4 erv = er4[v];
    const float NEG = -1e30f;

    float m0 = NEG, m1 = NEG, m2 = NEG, m3 = NEG;
    float d0s = 0.f, d1s = 0.f, d2s = 0.f, d3s = 0.f;
    float a0 = 0.f, a1 = 0.f;

    for (int eb = p0; eb < p1; eb += 64) {
        const int cnt = min(64, p1 - eb);
        int s = 0; float w = 0.f;
        float e0 = NEG, e1 = NEG, e2 = NEG, e3 = NEG;
        if (lane < cnt) {
            s = csr_src[eb + lane];
            w = csr_w[eb + lane];
            float4 elv = el4[s];
            float t;
            t = elv.x + erv.x; e0 = (t >= 0.f) ? t : 0.2f * t;
            t = elv.y + erv.y; e1 = (t >= 0.f) ? t : 0.2f * t;
            t = elv.z + erv.z; e2 = (t >= 0.f) ? t : 0.2f * t;
            t = elv.w + erv.w; e3 = (t >= 0.f) ? t : 0.2f * t;
        }
        float c0 = e0, c1 = e1, c2 = e2, c3 = e3;
        #pragma unroll
        for (int d = 1; d < 64; d <<= 1) {
            c0 = fmaxf(c0, __shfl_xor(c0, d));
            c1 = fmaxf(c1, __shfl_xor(c1, d));
            c2 = fmaxf(c2, __shfl_xor(c2, d));
            c3 = fmaxf(c3, __shfl_xor(c3, d));
        }
        float n0 = fmaxf(m0, c0), n1 = fmaxf(m1, c1), n2 = fmaxf(m2, c2), n3 = fmaxf(m3, c3);
        float q0 = __expf(e0 - n0), q1 = __expf(e1 - n1), q2 = __expf(e2 - n2), q3 = __expf(e3 - n3);
        float s0 = q0, s1 = q1, s2 = q2, s3 = q3;
        #pragma unroll
        for (int d = 1; d < 64; d <<= 1) {
            s0 += __shfl_xor(s0, d);
            s1 += __shfl_xor(s1, d);
            s2 += __shfl_xor(s2, d);
            s3 += __shfl_xor(s3, d);
        }
        float r0 = __expf(m0 - n0), r1 = __expf(m1 - n1), r2 = __expf(m2 - n2), r3 = __expf(m3 - n3);
        d0s = d0s * r0 + s0; d1s = d1s * r1 + s1; d2s = d2s * r2 + s2; d3s = d3s * r3 + s3;
        float scl = (hd == 0) ? r0 : (hd == 1) ? r1 : (hd == 2) ? r2 : r3;
        a0 *= scl; a1 *= scl;
        m0 = n0; m1 = n1; m2 = n2; m3 = n3;
        float pw0 = q0 * w, pw1 = q1 * w, pw2 = q2 * w, pw3 = q3 * w;
        for (int e = 0; e < cnt; ++e) {
            int se = __shfl(s, e);
            float t0 = __shfl(pw0, e), t1 = __shfl(pw1, e), t2 = __shfl(pw2, e), t3 = __shfl(pw3, e);
            float ae = (hd == 0) ? t0 : (hd == 1) ? t1 : (hd == 2) ? t2 : t3;
            unsigned int fu = *(const unsigned int*)(featu + (long)se * 128 + f0);
            a0 = fmaf(ae, bf2f((unsigned short)(fu & 0xffffu)), a0);
            a1 = fmaf(ae, bf2f((unsigned short)(fu >> 16)), a1);
        }
    }
    float den = (hd == 0) ? d0s : (hd == 1) ? d1s : (hd == 2) ? d2s : d3s;
    float invd = (p1 > p0) ? (1.0f / den) : 0.f;
    float o0 = a0 * invd, o1 = a1 * invd;
    float2 rv = *(const float2*)(res + (long)v * 128 + f0);
    float bs0, bs1, g0, g1, lb0, lb1;
    if (isbf) {
        const unsigned short* bsp = (const unsigned short*)bias;
        const unsigned short* gp  = (const unsigned short*)lng;
        const unsigned short* bp  = (const unsigned short*)lnb;
        bs0 = bf2f(bsp[f0]); bs1 = bf2f(bsp[f0 + 1]);
        g0  = bf2f(gp[f0]);  g1  = bf2f(gp[f0 + 1]);
        lb0 = bf2f(bp[f0]);  lb1 = bf2f(bp[f0 + 1]);
    } else {
        bs0 = ((const float*)bias)[f0]; bs1 = ((const float*)bias)[f0 + 1];
        g0  = ((const float*)lng)[f0];  g1  = ((const float*)lng)[f0 + 1];
        lb0 = ((const float*)lnb)[f0];  lb1 = ((const float*)lnb)[f0 + 1];
    }
    o0 += rv.x + bs0;
    o1 += rv.y + bs1;
    if (apply_elu) {
        o0 = (o0 > 0.f) ? o0 : expm1f(o0);
        o1 = (o1 > 0.f) ? o1 : expm1f(o1);
    }
    // LayerNorm over 128 features (wave-wide)
    float ssum = o0 + o1;
    #pragma unroll
    for (int d = 1; d < 64; d <<= 1) ssum += __shfl_xor(ssum, d);
    float mu = ssum * (1.0f / 128.0f);
    float dd0 = o0 - mu, dd1 = o1 - mu;
    float vsum = dd0 * dd0 + dd1 * dd1;
    #pragma unroll
    for (int d = 1; d < 64; d <<= 1) vsum += __shfl_xor(vsum, d);
    float rs = rsqrtf(vsum * (1.0f / 128.0f) + 1e-5f);
    float w0 = dd0 * rs * g0 + lb0;
    float w1 = dd1 * rs * g1 + lb1;
    if (final_mode && isbf) {
        ushort2 o; o.x = f2bf(w0); o.y = f2bf(w1);
        *(ushort2*)(out_u16 + (long)v * 128 + f0) = o;
    } else {
        *(float2*)(out_f32 + (long)v * 128 + f0) = make_float2(w0, w1);
    }
}

// ---------------- driver ----------------

extern "C" void kernel_launch(void* const* d_in, const int* in_sizes, int n_in,
                              void* d_out, int out_size, void* d_ws, size_t ws_size,
                              hipStream_t stream) {
    const void* x    = d_in[0];
    const int* src   = (const int*)d_in[1];
    const int* dst   = (const int*)d_in[2];
    const void* ew   = d_in[3];
    const void* W0   = d_in[4];
    const void* al0  = d_in[5];
    const void* ar0  = d_in[6];
    const void* b0   = d_in[7];
    const void* resW0= d_in[8];
    const void* ln0g = d_in[9];
    const void* ln0b = d_in[10];
    const void* W1   = d_in[11];
    const void* al1  = d_in[12];
    const void* ar1  = d_in[13];
    const void* b1   = d_in[14];
    const void* ln1g = d_in[15];
    const void* ln1b = d_in[16];
    const void* W2   = d_in[17];
    const void* al2  = d_in[18];
    const void* ar2  = d_in[19];
    const void* b2   = d_in[20];
    const void* ln2g = d_in[21];
    const void* ln2b = d_in[22];

    const int HD  = 128;
    const int Fin = in_sizes[4] / HD;        // 256
    const int N   = in_sizes[0] / Fin;       // 100000
    const int E   = in_sizes[1];             // 1600000

    char* ws = (char*)d_ws;
    size_t off = 0;
    auto alloc = [&](size_t bytes) -> void* {
        void* p = ws + off;
        off = (off + bytes + 255) & ~(size_t)255;
        return p;
    };
    int*   flag    = (int*)alloc(256);
    unsigned short* feat = (unsigned short*)alloc((size_t)N * 128 * 2);  // bf16
    float* res0    = (float*)alloc((size_t)N * 128 * 4);
    float* h       = (float*)alloc((size_t)N * 128 * 4);
    float* el      = (float*)alloc((size_t)N * 4 * 4);
    float* er      = (float*)alloc((size_t)N * 4 * 4);
    int*   rowptr  = (int*)alloc((size_t)(N + 1) * 4);
    int*   deg     = (int*)alloc((size_t)N * 4);
    int*   cur     = (int*)alloc((size_t)N * 4);
    int*   csr_src = (int*)alloc((size_t)E * 4);
    float* csr_w   = (float*)alloc((size_t)E * 4);

    const int zb = (N + 255) / 256;
    const int eb = (E + 255) / 256;
    const int gblocks = (N + 63) / 64;
    const int ablocks = (N + 3) / 4;
    const int lblocks = (N * 4 + 255) / 256;

    detect_kernel<<<1, 256, 0, stream>>>((const unsigned short*)W0, flag);

    // CSR build (dst shared across all 3 layers)
    zero_kernel<<<zb, 256, 0, stream>>>(deg, N);
    zero_kernel<<<zb, 256, 0, stream>>>(cur, N);
    degree_kernel<<<eb, 256, 0, stream>>>(dst, deg, E);
    scan_kernel<<<1, 1024, 0, stream>>>(deg, rowptr, N);
    scatter_kernel<<<eb, 256, 0, stream>>>(src, dst, ew, flag, rowptr, cur, csr_src, csr_w, E);

    // ---- layer 0 (residual = x @ resW0, ELU) ----
    gemm_kernel<1><<<gblocks, 256, 0, stream>>>(x, nullptr, W0,    feat, flag, 1, N, Fin);
    gemm_kernel<1><<<gblocks, 256, 0, stream>>>(x, nullptr, resW0, res0, flag, 0, N, Fin);
    elr_kernel<<<lblocks, 256, 0, stream>>>(feat, al0, ar0, flag, el, er, N);
    aggregate_kernel<<<ablocks, 256, 0, stream>>>(feat, (const float4*)el, (const float4*)er,
        res0, b0, ln0g, ln0b, flag, rowptr, csr_src, csr_w, h, nullptr, N, 1, 0);

    // ---- layer 1 (identity residual, ELU) ----
    gemm_kernel<0><<<gblocks, 256, 0, stream>>>(nullptr, h, W1, feat, flag, 1, N, HD);
    elr_kernel<<<lblocks, 256, 0, stream>>>(feat, al1, ar1, flag, el, er, N);
    aggregate_kernel<<<ablocks, 256, 0, stream>>>(feat, (const float4*)el, (const float4*)er,
        h, b1, ln1g, ln1b, flag, rowptr, csr_src, csr_w, h, nullptr, N, 1, 0);

    // ---- layer 2 (identity residual, no activation) ----
    gemm_kernel<0><<<gblocks, 256, 0, stream>>>(nullptr, h, W2, feat, flag, 1, N, HD);
    elr_kernel<<<lblocks, 256, 0, stream>>>(feat, al2, ar2, flag, el, er, N);
    aggregate_kernel<<<ablocks, 256, 0, stream>>>(feat, (const float4*)el, (const float4*)er,
        h, b2, ln2g, ln2b, flag, rowptr, csr_src, csr_w, (float*)d_out, (unsigned short*)d_out, N, 0, 1);
}

// Round 3
// 910.350 us; speedup vs baseline: 1.3179x; 1.3179x over previous
//
#include <hip/hip_runtime.h>
#include <hip/hip_bf16.h>
#include <math.h>

#define DEV __device__ __forceinline__

typedef short v8s __attribute__((ext_vector_type(8)));
typedef float v4f __attribute__((ext_vector_type(4)));

DEV float bf2f(unsigned short u) {
    union { unsigned int i; float f; } c; c.i = ((unsigned int)u) << 16; return c.f;
}
DEV unsigned short f2bf(float f) {
    union { float f; unsigned int u; } c; c.f = f;
    unsigned int u = c.u;
    unsigned int r = u + 0x7fffu + ((u >> 16) & 1u);
    return (unsigned short)(r >> 16);
}

// ---------------- input-dtype detector ----------------
__global__ void detect_kernel(const unsigned short* __restrict__ w, int* __restrict__ flag) {
    __shared__ int cnt;
    if (threadIdx.x == 0) cnt = 0;
    __syncthreads();
    int c = 0;
    for (int i = threadIdx.x; i < 2048; i += 256) {
        unsigned short u = w[i * 2];
        int e = (u >> 7) & 0xff;
        if (e >= 110 && e <= 132) c++;
    }
    atomicAdd(&cnt, c);
    __syncthreads();
    if (threadIdx.x == 0) *flag = (cnt > 1024) ? 1 : 0;
}

// ---------------- CSR build ----------------

__global__ void zero_kernel(int* __restrict__ p, int n) {
    int i = blockIdx.x * 256 + threadIdx.x;
    if (i < n) p[i] = 0;
}

__global__ void degree_kernel(const int* __restrict__ dst, int* __restrict__ deg, int E) {
    int i = blockIdx.x * 256 + threadIdx.x;
    if (i < E) atomicAdd(&deg[dst[i]], 1);
}

__global__ __launch_bounds__(1024)
void scan_kernel(const int* __restrict__ deg, int* __restrict__ rowptr, int n) {
    __shared__ int wtot[16];
    const int tid  = threadIdx.x;
    const int lane = tid & 63;
    const int wid  = tid >> 6;
    int carry = 0;
    for (int base = 0; base < n; base += 4096) {
        int i0 = base + tid * 4;
        int v0 = (i0     < n) ? deg[i0]     : 0;
        int v1 = (i0 + 1 < n) ? deg[i0 + 1] : 0;
        int v2 = (i0 + 2 < n) ? deg[i0 + 2] : 0;
        int v3 = (i0 + 3 < n) ? deg[i0 + 3] : 0;
        int s = v0 + v1 + v2 + v3;
        int sc = s;
        #pragma unroll
        for (int d = 1; d < 64; d <<= 1) {
            int t = __shfl_up(sc, d);
            if (lane >= d) sc += t;
        }
        if (lane == 63) wtot[wid] = sc;
        __syncthreads();
        int woff = 0, tot = 0;
        #pragma unroll
        for (int w = 0; w < 16; ++w) {
            int t = wtot[w];
            if (w < wid) woff += t;
            tot += t;
        }
        int p = carry + woff + (sc - s);
        if (i0     < n) rowptr[i0]     = p; p += v0;
        if (i0 + 1 < n) rowptr[i0 + 1] = p; p += v1;
        if (i0 + 2 < n) rowptr[i0 + 2] = p; p += v2;
        if (i0 + 3 < n) rowptr[i0 + 3] = p;
        carry += tot;
        __syncthreads();
    }
    if (tid == 0) rowptr[n] = carry;
}

__global__ void scatter_kernel(const int* __restrict__ src, const int* __restrict__ dst,
                               const void* __restrict__ ew, const int* __restrict__ flagp,
                               const int* __restrict__ rowptr, int* __restrict__ cur,
                               int* __restrict__ csr_src, float* __restrict__ csr_w, int E) {
    int i = blockIdx.x * 256 + threadIdx.x;
    if (i < E) {
        int isbf = *flagp;
        int d = dst[i];
        int pos = atomicAdd(&cur[d], 1);
        int slot = rowptr[d] + pos;
        csr_src[slot] = src[i];
        csr_w[slot] = isbf ? bf2f(((const unsigned short*)ew)[i]) : ((const float*)ew)[i];
    }
}

// ---------------- x -> bf16 convert (only needed when inputs are fp32) ----------------
__global__ void convx_kernel(const void* __restrict__ x, unsigned short* __restrict__ xbf,
                             const int* __restrict__ flagp, long n8) {
    if (*flagp) return;   // already bf16; gemm reads x directly
    long i = ((long)blockIdx.x * 256 + threadIdx.x) * 8;
    if (i >= n8 * 8) return;
    const float* xf = (const float*)x + i;
    unsigned int o[4];
    #pragma unroll
    for (int j = 0; j < 4; ++j)
        o[j] = (unsigned int)f2bf(xf[j*2]) | ((unsigned int)f2bf(xf[j*2+1]) << 16);
    *(uint4*)(xbf + i) = make_uint4(o[0], o[1], o[2], o[3]);
}

// ---------------- weight -> packed MFMA B-fragment layout ----------------
// Btp index i = ((c*8 + t)*64 + l)*8 + j  holds  B[k = c*32 + (l>>4)*8 + j][n = t*16 + (l&15)]
__global__ void wtrans_kernel(const void* __restrict__ B, unsigned short* __restrict__ Btp,
                              const int* __restrict__ flagp, int K) {
    int i = blockIdx.x * 256 + threadIdx.x;
    if (i >= 128 * K) return;
    int j = i & 7;
    int l = (i >> 3) & 63;
    int t = (i >> 9) & 7;
    int c = i >> 12;
    int k = c * 32 + ((l >> 4) * 8) + j;
    int n = t * 16 + (l & 15);
    unsigned short v;
    if (*flagp) v = ((const unsigned short*)B)[k * 128 + n];
    else        v = f2bf(((const float*)B)[k * 128 + n]);
    Btp[i] = v;
}

// ---------------- MFMA GEMM: C[M,128](bf16) = A[M,K](bf16) @ B[K,128] ----------------
// wave = 16x128 tile; no LDS, no barriers. B comes pre-packed in fragment order.
__global__ __launch_bounds__(256)
void gemm_mfma(const unsigned short* __restrict__ Aext, const unsigned short* __restrict__ Aconv,
               const int* __restrict__ flagp,
               const unsigned short* __restrict__ Btp,
               unsigned short* __restrict__ Cout, int M, int K) {
    const unsigned short* A = (*flagp) ? Aext : Aconv;
    const int lane = threadIdx.x & 63;
    const int wid  = threadIdx.x >> 6;
    const long tile = (long)blockIdx.x * 4 + wid;
    const long m0 = tile * 16;
    if (m0 >= M) return;
    const int r = lane & 15, quad = lane >> 4;
    long arow = m0 + r; if (arow >= M) arow = M - 1;
    const unsigned short* ap = A + arow * K + quad * 8;
    v4f acc[8];
    #pragma unroll
    for (int t = 0; t < 8; ++t) acc[t] = (v4f){0.f, 0.f, 0.f, 0.f};
    for (int k0 = 0; k0 < K; k0 += 32) {
        v8s af = *(const v8s*)(ap + k0);
        const unsigned short* bp = Btp + ((size_t)(k0 >> 5) * 8) * 512 + lane * 8;
        #pragma unroll
        for (int t = 0; t < 8; ++t) {
            v8s bf = *(const v8s*)(bp + t * 512);
            acc[t] = __builtin_amdgcn_mfma_f32_16x16x32_bf16(af, bf, acc[t], 0, 0, 0);
        }
    }
    #pragma unroll
    for (int t = 0; t < 8; ++t) {
        const int col = t * 16 + r;
        #pragma unroll
        for (int reg = 0; reg < 4; ++reg) {
            long grow = m0 + quad * 4 + reg;
            if (grow < M) Cout[grow * 128 + col] = f2bf(acc[t][reg]);
        }
    }
}

// ---------------- el/er ----------------

__global__ __launch_bounds__(256)
void elr_kernel(const unsigned short* __restrict__ featu,
                const void* __restrict__ al, const void* __restrict__ ar,
                const int* __restrict__ flagp,
                float* __restrict__ el, float* __restrict__ er, int N) {
    int idx = blockIdx.x * 256 + threadIdx.x;
    if (idx >= N * 4) return;
    const int isbf = *flagp;
    int n = idx >> 2, h = idx & 3;
    const unsigned short* fr = featu + (long)n * 128 + h * 32;
    float av[32], bv[32];
    if (isbf) {
        const unsigned short* alp = (const unsigned short*)al + h * 32;
        const unsigned short* arp = (const unsigned short*)ar + h * 32;
        #pragma unroll
        for (int i = 0; i < 32; ++i) { av[i] = bf2f(alp[i]); bv[i] = bf2f(arp[i]); }
    } else {
        const float* alp = (const float*)al + h * 32;
        const float* arp = (const float*)ar + h * 32;
        #pragma unroll
        for (int i = 0; i < 32; ++i) { av[i] = alp[i]; bv[i] = arp[i]; }
    }
    float sl = 0.f, sr = 0.f;
    #pragma unroll
    for (int i = 0; i < 32; i += 8) {
        uint4 u = *(const uint4*)&fr[i];
        float f[8];
        f[0] = bf2f((unsigned short)(u.x & 0xffffu)); f[1] = bf2f((unsigned short)(u.x >> 16));
        f[2] = bf2f((unsigned short)(u.y & 0xffffu)); f[3] = bf2f((unsigned short)(u.y >> 16));
        f[4] = bf2f((unsigned short)(u.z & 0xffffu)); f[5] = bf2f((unsigned short)(u.z >> 16));
        f[6] = bf2f((unsigned short)(u.w & 0xffffu)); f[7] = bf2f((unsigned short)(u.w >> 16));
        #pragma unroll
        for (int j = 0; j < 8; ++j) { sl += f[j] * av[i + j]; sr += f[j] * bv[i + j]; }
    }
    el[idx] = sl; er[idx] = sr;
}

// ---------------- fused: softmax + aggregate + residual + bias + ELU + LayerNorm ----------------
// 1 wave / node. Phase 1: lane=edge, online-softmax stats; per-edge alpha*w -> LDS.
// Phase 2: lane = (edge-subgroup eg=lane>>4) x (feature-octet fl=lane&15); 16B coalesced gathers.

__global__ __launch_bounds__(256)
void aggregate_kernel(const unsigned short* __restrict__ featu,
                      const float4* __restrict__ el4,
                      const float4* __restrict__ er4,
                      const unsigned short* __restrict__ res_bf,
                      const void* __restrict__ bias,
                      const void* __restrict__ lng,
                      const void* __restrict__ lnb,
                      const int* __restrict__ flagp,
                      const int* __restrict__ rowptr,
                      const int* __restrict__ csr_src,
                      const float* __restrict__ csr_w,
                      unsigned short* __restrict__ out_bf,
                      float* __restrict__ out_f32,
                      int N, int apply_elu, int final_mode) {
    __shared__ int   s_src[4][64];
    __shared__ float s_pw[4][256];
    const int lane = threadIdx.x & 63;
    const int wid  = threadIdx.x >> 6;
    const int v = blockIdx.x * 4 + wid;
    if (v >= N) return;
    const int isbf = *flagp;
    const int eg = lane >> 4;     // edge subgroup 0..3
    const int fl = lane & 15;     // feature octet 0..15
    const int hd = fl >> 2;       // head of this lane's 8 features
    const int fb = fl * 8;        // feature base
    const int p0 = rowptr[v], p1 = rowptr[v + 1];
    const float4 erv = er4[v];
    const float NEG = -1e30f;

    float m0 = NEG, m1 = NEG, m2 = NEG, m3 = NEG;
    float d0s = 0.f, d1s = 0.f, d2s = 0.f, d3s = 0.f;
    float acc[8];
    #pragma unroll
    for (int j = 0; j < 8; ++j) acc[j] = 0.f;

    for (int eb = p0; eb < p1; eb += 64) {
        const int cnt = min(64, p1 - eb);
        // ---- phase 1: lane = edge ----
        int s = 0; float w = 0.f;
        float e0 = NEG, e1 = NEG, e2 = NEG, e3 = NEG;
        if (lane < cnt) {
            s = csr_src[eb + lane];
            w = csr_w[eb + lane];
            float4 elv = el4[s];
            float t;
            t = elv.x + erv.x; e0 = (t >= 0.f) ? t : 0.2f * t;
            t = elv.y + erv.y; e1 = (t >= 0.f) ? t : 0.2f * t;
            t = elv.z + erv.z; e2 = (t >= 0.f) ? t : 0.2f * t;
            t = elv.w + erv.w; e3 = (t >= 0.f) ? t : 0.2f * t;
        }
        float c0 = e0, c1 = e1, c2 = e2, c3 = e3;
        #pragma unroll
        for (int d = 1; d < 64; d <<= 1) {
            c0 = fmaxf(c0, __shfl_xor(c0, d));
            c1 = fmaxf(c1, __shfl_xor(c1, d));
            c2 = fmaxf(c2, __shfl_xor(c2, d));
            c3 = fmaxf(c3, __shfl_xor(c3, d));
        }
        float n0 = fmaxf(m0, c0), n1 = fmaxf(m1, c1), n2 = fmaxf(m2, c2), n3 = fmaxf(m3, c3);
        float q0 = __expf(e0 - n0), q1 = __expf(e1 - n1), q2 = __expf(e2 - n2), q3 = __expf(e3 - n3);
        float s0 = q0, s1 = q1, s2 = q2, s3 = q3;
        #pragma unroll
        for (int d = 1; d < 64; d <<= 1) {
            s0 += __shfl_xor(s0, d);
            s1 += __shfl_xor(s1, d);
            s2 += __shfl_xor(s2, d);
            s3 += __shfl_xor(s3, d);
        }
        float r0 = __expf(m0 - n0), r1 = __expf(m1 - n1), r2 = __expf(m2 - n2), r3 = __expf(m3 - n3);
        d0s = d0s * r0 + s0; d1s = d1s * r1 + s1; d2s = d2s * r2 + s2; d3s = d3s * r3 + s3;
        m0 = n0; m1 = n1; m2 = n2; m3 = n3;
        // rescale accumulators by own head's r
        float scl = (hd == 0) ? r0 : (hd == 1) ? r1 : (hd == 2) ? r2 : r3;
        #pragma unroll
        for (int j = 0; j < 8; ++j) acc[j] *= scl;
        // park per-edge weighted numerators (inactive lanes: q=0 -> pw=0)
        s_src[wid][lane] = s;
        *(float4*)&s_pw[wid][lane * 4] = make_float4(q0 * w, q1 * w, q2 * w, q3 * w);
        // ---- phase 2: lane = (eg, fl), 4 edges in parallel ----
        const int cntr = (cnt + 3) & ~3;
        for (int e = 0; e < cntr; e += 4) {
            int ee = e + eg;
            int se = s_src[wid][ee];
            float ae = s_pw[wid][ee * 4 + hd];
            uint4 u = *(const uint4*)(featu + (size_t)se * 128 + fb);
            acc[0] = fmaf(ae, bf2f((unsigned short)(u.x & 0xffffu)), acc[0]);
            acc[1] = fmaf(ae, bf2f((unsigned short)(u.x >> 16)),     acc[1]);
            acc[2] = fmaf(ae, bf2f((unsigned short)(u.y & 0xffffu)), acc[2]);
            acc[3] = fmaf(ae, bf2f((unsigned short)(u.y >> 16)),     acc[3]);
            acc[4] = fmaf(ae, bf2f((unsigned short)(u.z & 0xffffu)), acc[4]);
            acc[5] = fmaf(ae, bf2f((unsigned short)(u.z >> 16)),     acc[5]);
            acc[6] = fmaf(ae, bf2f((unsigned short)(u.w & 0xffffu)), acc[6]);
            acc[7] = fmaf(ae, bf2f((unsigned short)(u.w >> 16)),     acc[7]);
        }
    }
    // reduce across the 4 edge subgroups (lanes differing in bits 4,5)
    #pragma unroll
    for (int j = 0; j < 8; ++j) {
        acc[j] += __shfl_xor(acc[j], 16);
        acc[j] += __shfl_xor(acc[j], 32);
    }
    float den = (hd == 0) ? d0s : (hd == 1) ? d1s : (hd == 2) ? d2s : d3s;
    float invd = (p1 > p0) ? (1.0f / den) : 0.f;
    // residual (bf16) + bias
    uint4 ru = *(const uint4*)(res_bf + (size_t)v * 128 + fb);
    float rv[8];
    rv[0] = bf2f((unsigned short)(ru.x & 0xffffu)); rv[1] = bf2f((unsigned short)(ru.x >> 16));
    rv[2] = bf2f((unsigned short)(ru.y & 0xffffu)); rv[3] = bf2f((unsigned short)(ru.y >> 16));
    rv[4] = bf2f((unsigned short)(ru.z & 0xffffu)); rv[5] = bf2f((unsigned short)(ru.z >> 16));
    rv[6] = bf2f((unsigned short)(ru.w & 0xffffu)); rv[7] = bf2f((unsigned short)(ru.w >> 16));
    float bsv[8], gv[8], lbv[8];
    if (isbf) {
        const unsigned short* bsp = (const unsigned short*)bias + fb;
        const unsigned short* gp  = (const unsigned short*)lng + fb;
        const unsigned short* bp  = (const unsigned short*)lnb + fb;
        #pragma unroll
        for (int j = 0; j < 8; ++j) { bsv[j] = bf2f(bsp[j]); gv[j] = bf2f(gp[j]); lbv[j] = bf2f(bp[j]); }
    } else {
        const float* bsp = (const float*)bias + fb;
        const float* gp  = (const float*)lng + fb;
        const float* bp  = (const float*)lnb + fb;
        #pragma unroll
        for (int j = 0; j < 8; ++j) { bsv[j] = bsp[j]; gv[j] = gp[j]; lbv[j] = bp[j]; }
    }
    float o[8];
    float ssum = 0.f;
    #pragma unroll
    for (int j = 0; j < 8; ++j) {
        float t = acc[j] * invd + rv[j] + bsv[j];
        if (apply_elu) t = (t > 0.f) ? t : expm1f(t);
        o[j] = t;
        ssum += t;
    }
    // LN over 128 = 16 fl-lanes x 8 (eg groups are redundant copies: reduce over fl bits only)
    #pragma unroll
    for (int d = 1; d < 16; d <<= 1) ssum += __shfl_xor(ssum, d);
    float mu = ssum * (1.0f / 128.0f);
    float vsum = 0.f;
    #pragma unroll
    for (int j = 0; j < 8; ++j) { float dd = o[j] - mu; vsum += dd * dd; }
    #pragma unroll
    for (int d = 1; d < 16; d <<= 1) vsum += __shfl_xor(vsum, d);
    float rs = rsqrtf(vsum * (1.0f / 128.0f) + 1e-5f);
    if (eg == 0) {
        if (final_mode && !isbf) {
            float* op = out_f32 + (size_t)v * 128 + fb;
            #pragma unroll
            for (int j = 0; j < 8; ++j) op[j] = (o[j] - mu) * rs * gv[j] + lbv[j];
        } else {
            unsigned int w[4];
            #pragma unroll
            for (int j = 0; j < 4; ++j) {
                unsigned short lo = f2bf((o[j*2]   - mu) * rs * gv[j*2]   + lbv[j*2]);
                unsigned short hi = f2bf((o[j*2+1] - mu) * rs * gv[j*2+1] + lbv[j*2+1]);
                w[j] = (unsigned int)lo | ((unsigned int)hi << 16);
            }
            *(uint4*)(out_bf + (size_t)v * 128 + fb) = make_uint4(w[0], w[1], w[2], w[3]);
        }
    }
}

// ---------------- driver ----------------

extern "C" void kernel_launch(void* const* d_in, const int* in_sizes, int n_in,
                              void* d_out, int out_size, void* d_ws, size_t ws_size,
                              hipStream_t stream) {
    const void* x    = d_in[0];
    const int* src   = (const int*)d_in[1];
    const int* dst   = (const int*)d_in[2];
    const void* ew   = d_in[3];
    const void* W0   = d_in[4];
    const void* al0  = d_in[5];
    const void* ar0  = d_in[6];
    const void* b0   = d_in[7];
    const void* resW0= d_in[8];
    const void* ln0g = d_in[9];
    const void* ln0b = d_in[10];
    const void* W1   = d_in[11];
    const void* al1  = d_in[12];
    const void* ar1  = d_in[13];
    const void* b1   = d_in[14];
    const void* ln1g = d_in[15];
    const void* ln1b = d_in[16];
    const void* W2   = d_in[17];
    const void* al2  = d_in[18];
    const void* ar2  = d_in[19];
    const void* b2   = d_in[20];
    const void* ln2g = d_in[21];
    const void* ln2b = d_in[22];

    const int HD  = 128;
    const int Fin = in_sizes[4] / HD;        // 256
    const int N   = in_sizes[0] / Fin;       // 100000
    const int E   = in_sizes[1];             // 1600000

    char* ws = (char*)d_ws;
    size_t off = 0;
    auto alloc = [&](size_t bytes) -> void* {
        void* p = ws + off;
        off = (off + bytes + 255) & ~(size_t)255;
        return p;
    };
    int*   flag    = (int*)alloc(256);
    unsigned short* xbf   = (unsigned short*)alloc((size_t)N * Fin * 2);
    unsigned short* feat  = (unsigned short*)alloc((size_t)N * 128 * 2);
    unsigned short* h_bf  = (unsigned short*)alloc((size_t)N * 128 * 2);
    unsigned short* res0  = (unsigned short*)alloc((size_t)N * 128 * 2);
    float* el      = (float*)alloc((size_t)N * 4 * 4);
    float* er      = (float*)alloc((size_t)N * 4 * 4);
    int*   rowptr  = (int*)alloc((size_t)(N + 1) * 4);
    int*   deg     = (int*)alloc((size_t)N * 4);
    int*   cur     = (int*)alloc((size_t)N * 4);
    int*   csr_src = (int*)alloc((size_t)E * 4);
    float* csr_w   = (float*)alloc((size_t)E * 4);
    unsigned short* Bt0  = (unsigned short*)alloc((size_t)128 * Fin * 2);
    unsigned short* Btr0 = (unsigned short*)alloc((size_t)128 * Fin * 2);
    unsigned short* Bt1  = (unsigned short*)alloc((size_t)128 * HD * 2);
    unsigned short* Bt2  = (unsigned short*)alloc((size_t)128 * HD * 2);

    const int zb = (N + 255) / 256;
    const int eb = (E + 255) / 256;
    const int gblocks = (N + 63) / 64;
    const int ablocks = (N + 3) / 4;
    const int lblocks = (N * 4 + 255) / 256;
    const long n8 = (long)N * Fin / 8;
    const int cxb = (int)((n8 + 255) / 256);
    const int wtb0 = (128 * Fin + 255) / 256;
    const int wtb1 = (128 * HD + 255) / 256;

    detect_kernel<<<1, 256, 0, stream>>>((const unsigned short*)W0, flag);

    // CSR build (dst shared across all 3 layers)
    zero_kernel<<<zb, 256, 0, stream>>>(deg, N);
    zero_kernel<<<zb, 256, 0, stream>>>(cur, N);
    degree_kernel<<<eb, 256, 0, stream>>>(dst, deg, E);
    scan_kernel<<<1, 1024, 0, stream>>>(deg, rowptr, N);
    scatter_kernel<<<eb, 256, 0, stream>>>(src, dst, ew, flag, rowptr, cur, csr_src, csr_w, E);

    // weight packing + x conversion
    convx_kernel<<<cxb, 256, 0, stream>>>(x, xbf, flag, n8);
    wtrans_kernel<<<wtb0, 256, 0, stream>>>(W0,    Bt0,  flag, Fin);
    wtrans_kernel<<<wtb0, 256, 0, stream>>>(resW0, Btr0, flag, Fin);
    wtrans_kernel<<<wtb1, 256, 0, stream>>>(W1,    Bt1,  flag, HD);
    wtrans_kernel<<<wtb1, 256, 0, stream>>>(W2,    Bt2,  flag, HD);

    // ---- layer 0 (residual = x @ resW0, ELU) ----
    gemm_mfma<<<gblocks, 256, 0, stream>>>((const unsigned short*)x, xbf, flag, Bt0,  feat, N, Fin);
    gemm_mfma<<<gblocks, 256, 0, stream>>>((const unsigned short*)x, xbf, flag, Btr0, res0, N, Fin);
    elr_kernel<<<lblocks, 256, 0, stream>>>(feat, al0, ar0, flag, el, er, N);
    aggregate_kernel<<<ablocks, 256, 0, stream>>>(feat, (const float4*)el, (const float4*)er,
        res0, b0, ln0g, ln0b, flag, rowptr, csr_src, csr_w, h_bf, nullptr, N, 1, 0);

    // ---- layer 1 (identity residual, ELU) ----
    gemm_mfma<<<gblocks, 256, 0, stream>>>(h_bf, h_bf, flag, Bt1, feat, N, HD);
    elr_kernel<<<lblocks, 256, 0, stream>>>(feat, al1, ar1, flag, el, er, N);
    aggregate_kernel<<<ablocks, 256, 0, stream>>>(feat, (const float4*)el, (const float4*)er,
        h_bf, b1, ln1g, ln1b, flag, rowptr, csr_src, csr_w, h_bf, nullptr, N, 1, 0);

    // ---- layer 2 (identity residual, no activation) ----
    gemm_mfma<<<gblocks, 256, 0, stream>>>(h_bf, h_bf, flag, Bt2, feat, N, HD);
    elr_kernel<<<lblocks, 256, 0, stream>>>(feat, al2, ar2, flag, el, er, N);
    aggregate_kernel<<<ablocks, 256, 0, stream>>>(feat, (const float4*)el, (const float4*)er,
        h_bf, b2, ln2g, ln2b, flag, rowptr, csr_src, csr_w, (unsigned short*)d_out, (float*)d_out, N, 0, 1);
}